// Round 1
// baseline (334.691 us; speedup 1.0000x reference)
//
#include <hip/hip_runtime.h>
#include <hip/hip_bf16.h>

// SwiGLU MLP: out = (silu(x@wg^T * S) * (x@wu^T * S)) @ wd^T * S,  S = 1/127
// x f32 [8192,1024]; wg,wu int32(int8-valued) [3072,1024]; wd [1024,3072]
// Strategy: cast x->bf16, weights->integer-valued bf16 (exact), fold S into
// epilogues. Two m97-structure NT GEMMs (128x128 tile, BK=64, global_load_lds,
// mfma_f32_16x16x32_bf16). W1 rows interleaved in 16-blocks (gate|up) so the
// SwiGLU epilogue needs no cross-lane ops.

typedef __attribute__((ext_vector_type(8))) __bf16 bf16x8;
typedef __attribute__((ext_vector_type(4))) float f32x4;

static constexpr float QS = 1.0f / 127.0f;

__device__ __forceinline__ void gload_lds16(const void* g, void* l) {
  __builtin_amdgcn_global_load_lds(
      (const __attribute__((address_space(1))) void*)g,
      (__attribute__((address_space(3))) void*)l,
      16, 0, 0);
}

// ---------------- conversion kernels ----------------

__global__ __launch_bounds__(256) void k_conv_x(const float* __restrict__ x,
                                                __bf16* __restrict__ xb, int n8) {
  int t = blockIdx.x * 256 + threadIdx.x;
  if (t >= n8) return;
  const float4* p = (const float4*)(x + (size_t)t * 8);
  float4 a = p[0], b = p[1];
  bf16x8 o;
  o[0] = (__bf16)a.x; o[1] = (__bf16)a.y; o[2] = (__bf16)a.z; o[3] = (__bf16)a.w;
  o[4] = (__bf16)b.x; o[5] = (__bf16)b.y; o[6] = (__bf16)b.z; o[7] = (__bf16)b.w;
  *(bf16x8*)(xb + (size_t)t * 8) = o;
}

// W1 row v (0..6143): bb=v>>5, t=v&31; t<16 -> w_gate[16*bb+t] else w_up[16*bb+t-16]
__global__ __launch_bounds__(256) void k_conv_w1(const int* __restrict__ wg,
                                                 const int* __restrict__ wu,
                                                 __bf16* __restrict__ w1) {
  int t = blockIdx.x * 256 + threadIdx.x;  // 6144*128 threads, 8 elems each
  int c8 = t & 127;
  int v = t >> 7;
  int bb = v >> 5, tt = v & 31;
  const int* src = (tt < 16) ? (wg + (size_t)(bb * 16 + tt) * 1024)
                             : (wu + (size_t)(bb * 16 + (tt & 15)) * 1024);
  const int4* p = (const int4*)(src + c8 * 8);
  int4 a = p[0], b = p[1];
  bf16x8 o;
  o[0] = (__bf16)(float)a.x; o[1] = (__bf16)(float)a.y;
  o[2] = (__bf16)(float)a.z; o[3] = (__bf16)(float)a.w;
  o[4] = (__bf16)(float)b.x; o[5] = (__bf16)(float)b.y;
  o[6] = (__bf16)(float)b.z; o[7] = (__bf16)(float)b.w;
  *(bf16x8*)(w1 + (size_t)v * 1024 + c8 * 8) = o;
}

__global__ __launch_bounds__(256) void k_conv_wd(const int* __restrict__ wdn,
                                                 __bf16* __restrict__ wdb, int n8) {
  int t = blockIdx.x * 256 + threadIdx.x;
  if (t >= n8) return;
  const int4* p = (const int4*)(wdn + (size_t)t * 8);
  int4 a = p[0], b = p[1];
  bf16x8 o;
  o[0] = (__bf16)(float)a.x; o[1] = (__bf16)(float)a.y;
  o[2] = (__bf16)(float)a.z; o[3] = (__bf16)(float)a.w;
  o[4] = (__bf16)(float)b.x; o[5] = (__bf16)(float)b.y;
  o[6] = (__bf16)(float)b.z; o[7] = (__bf16)(float)b.w;
  *(bf16x8*)(wdb + (size_t)t * 8) = o;
}

// ---------------- GEMM (NT, B^T input), 128x128 tile, BK=64 ----------------
// A [M,K] bf16 row-major, B [N,K] bf16 row-major. 4 waves in 2x2, each 64x64.
// SWIGLU epilogue: B-tile columns are (gate|up) 16-blocks; pair of adjacent
// 16-col frags (j=2p, 2p+1) gives gate/up for the same h column in SAME lane.
template <bool SWIGLU>
__global__ __launch_bounds__(256) void k_gemm_bt(const __bf16* __restrict__ A,
                                                 const __bf16* __restrict__ B,
                                                 void* __restrict__ Out,
                                                 int K, int ldo) {
  __shared__ __bf16 sA[128][64];
  __shared__ __bf16 sB[128][64];
  const int tid = threadIdx.x;
  const int lane = tid & 63;
  const int wid = tid >> 6;
  const int wm = wid >> 1, wn = wid & 1;
  const int row0 = blockIdx.y * 128, col0 = blockIdx.x * 128;
  const int r16 = lane & 15;  // row within a 16-block (m or n)
  const int kq = lane >> 4;   // k-quarter selector

  f32x4 acc[4][4] = {};

  const int nkt = K >> 6;
  for (int kt = 0; kt < nkt; ++kt) {
    __syncthreads();  // previous tile's compute done before overwrite
#pragma unroll
    for (int it = 0; it < 4; ++it) {
      int chunk = it * 256 + tid;  // 0..1023 chunks of 16B
      int r = chunk >> 3, kc = chunk & 7;
      gload_lds16(A + (size_t)(row0 + r) * K + kt * 64 + kc * 8,
                  ((__bf16*)sA) + chunk * 8);
      gload_lds16(B + (size_t)(col0 + r) * K + kt * 64 + kc * 8,
                  ((__bf16*)sB) + chunk * 8);
    }
    __syncthreads();  // drains vmcnt(0): tiles resident
#pragma unroll
    for (int ks = 0; ks < 2; ++ks) {
      const int k0 = ks * 32 + kq * 8;
      bf16x8 av[4], bv[4];
#pragma unroll
      for (int i = 0; i < 4; ++i)
        av[i] = *(const bf16x8*)&sA[wm * 64 + i * 16 + r16][k0];
#pragma unroll
      for (int j = 0; j < 4; ++j)
        bv[j] = *(const bf16x8*)&sB[wn * 64 + j * 16 + r16][k0];
#pragma unroll
      for (int i = 0; i < 4; ++i)
#pragma unroll
        for (int j = 0; j < 4; ++j)
          acc[i][j] = __builtin_amdgcn_mfma_f32_16x16x32_bf16(av[i], bv[j],
                                                              acc[i][j], 0, 0, 0);
    }
  }

  if constexpr (SWIGLU) {
    __bf16* hout = (__bf16*)Out;
    const int hbase = (col0 + wn * 64) >> 1;
#pragma unroll
    for (int i = 0; i < 4; ++i) {
#pragma unroll
      for (int p = 0; p < 2; ++p) {
#pragma unroll
        for (int r = 0; r < 4; ++r) {
          int row = row0 + wm * 64 + i * 16 + kq * 4 + r;
          float g = acc[i][2 * p][r] * QS;
          float u = acc[i][2 * p + 1][r] * QS;
          float hv = (g / (1.0f + __expf(-g))) * u;
          hout[(size_t)row * ldo + hbase + p * 16 + r16] = (__bf16)hv;
        }
      }
    }
  } else {
    float* out = (float*)Out;
#pragma unroll
    for (int i = 0; i < 4; ++i)
#pragma unroll
      for (int j = 0; j < 4; ++j)
#pragma unroll
        for (int r = 0; r < 4; ++r) {
          int row = row0 + wm * 64 + i * 16 + kq * 4 + r;
          int col = col0 + wn * 64 + j * 16 + r16;
          out[(size_t)row * ldo + col] = acc[i][j][r] * QS;
        }
  }
}

// ---------------- launch ----------------

extern "C" void kernel_launch(void* const* d_in, const int* in_sizes, int n_in,
                              void* d_out, int out_size, void* d_ws, size_t ws_size,
                              hipStream_t stream) {
  const float* x = (const float*)d_in[0];
  const int* wg = (const int*)d_in[1];
  const int* wu = (const int*)d_in[2];
  const int* wd = (const int*)d_in[3];

  char* ws = (char*)d_ws;
  __bf16* xb  = (__bf16*)(ws);                          // 8192*1024*2  = 16,777,216 B
  __bf16* w1  = (__bf16*)(ws + 16777216);               // 6144*1024*2  = 12,582,912 B
  __bf16* wdb = (__bf16*)(ws + 16777216 + 12582912);    // 1024*3072*2  =  6,291,456 B
  __bf16* h   = (__bf16*)(ws + 35651584);               // 8192*3072*2  = 50,331,648 B

  k_conv_x<<<4096, 256, 0, stream>>>(x, xb, 1048576);          // 8M/8
  k_conv_w1<<<3072, 256, 0, stream>>>(wg, wu, w1);             // 6144*128
  k_conv_wd<<<1536, 256, 0, stream>>>(wd, wdb, 393216);        // 1024*384

  // GEMM1: [8192,1024] x [6144,1024]^T -> h [8192,3072] (SwiGLU fused)
  k_gemm_bt<true><<<dim3(48, 64), 256, 0, stream>>>(xb, w1, h, 1024, 3072);
  // GEMM2: [8192,3072] x [1024,3072]^T -> out f32 [8192,1024]
  k_gemm_bt<false><<<dim3(8, 64), 256, 0, stream>>>(h, wdb, (float*)d_out, 3072, 1024);
}

// Round 2
// 331.943 us; speedup vs baseline: 1.0083x; 1.0083x over previous
//
#include <hip/hip_runtime.h>
#include <hip/hip_bf16.h>

// SwiGLU MLP: out = (silu(x@wg^T * S) * (x@wu^T * S)) @ wd^T * S,  S = 1/127
// Round 2: T2 XOR-swizzle (linear LDS dest + inverse-swizzled global src +
// swizzled ds_read, rule #21) to kill the 16-way bank conflict; split-K=2 on
// GEMM2 to double occupancy (512 -> 1024 blocks).

typedef __attribute__((ext_vector_type(8))) __bf16 bf16x8;
typedef __attribute__((ext_vector_type(4))) float f32x4;

static constexpr float QS = 1.0f / 127.0f;

__device__ __forceinline__ void gload_lds16(const void* g, void* l) {
  __builtin_amdgcn_global_load_lds(
      (const __attribute__((address_space(1))) void*)g,
      (__attribute__((address_space(3))) void*)l,
      16, 0, 0);
}

// ---------------- conversion kernels ----------------

__global__ __launch_bounds__(256) void k_conv_x(const float* __restrict__ x,
                                                __bf16* __restrict__ xb, int n8) {
  int t = blockIdx.x * 256 + threadIdx.x;
  if (t >= n8) return;
  const float4* p = (const float4*)(x + (size_t)t * 8);
  float4 a = p[0], b = p[1];
  bf16x8 o;
  o[0] = (__bf16)a.x; o[1] = (__bf16)a.y; o[2] = (__bf16)a.z; o[3] = (__bf16)a.w;
  o[4] = (__bf16)b.x; o[5] = (__bf16)b.y; o[6] = (__bf16)b.z; o[7] = (__bf16)b.w;
  *(bf16x8*)(xb + (size_t)t * 8) = o;
}

// W1 row v (0..6143): bb=v>>5, t=v&31; t<16 -> w_gate[16*bb+t] else w_up[16*bb+t-16]
__global__ __launch_bounds__(256) void k_conv_w1(const int* __restrict__ wg,
                                                 const int* __restrict__ wu,
                                                 __bf16* __restrict__ w1) {
  int t = blockIdx.x * 256 + threadIdx.x;  // 6144*128 threads, 8 elems each
  int c8 = t & 127;
  int v = t >> 7;
  int bb = v >> 5, tt = v & 31;
  const int* src = (tt < 16) ? (wg + (size_t)(bb * 16 + tt) * 1024)
                             : (wu + (size_t)(bb * 16 + (tt & 15)) * 1024);
  const int4* p = (const int4*)(src + c8 * 8);
  int4 a = p[0], b = p[1];
  bf16x8 o;
  o[0] = (__bf16)(float)a.x; o[1] = (__bf16)(float)a.y;
  o[2] = (__bf16)(float)a.z; o[3] = (__bf16)(float)a.w;
  o[4] = (__bf16)(float)b.x; o[5] = (__bf16)(float)b.y;
  o[6] = (__bf16)(float)b.z; o[7] = (__bf16)(float)b.w;
  *(bf16x8*)(w1 + (size_t)v * 1024 + c8 * 8) = o;
}

__global__ __launch_bounds__(256) void k_conv_wd(const int* __restrict__ wdn,
                                                 __bf16* __restrict__ wdb, int n8) {
  int t = blockIdx.x * 256 + threadIdx.x;
  if (t >= n8) return;
  const int4* p = (const int4*)(wdn + (size_t)t * 8);
  int4 a = p[0], b = p[1];
  bf16x8 o;
  o[0] = (__bf16)(float)a.x; o[1] = (__bf16)(float)a.y;
  o[2] = (__bf16)(float)a.z; o[3] = (__bf16)(float)a.w;
  o[4] = (__bf16)(float)b.x; o[5] = (__bf16)(float)b.y;
  o[6] = (__bf16)(float)b.z; o[7] = (__bf16)(float)b.w;
  *(bf16x8*)(wdb + (size_t)t * 8) = o;
}

// ---------------- GEMM (NT, B^T input), 128x128 tile, BK=64 ----------------
// A [*,lda] bf16 row-major, B [*,lda] bf16 row-major; computes over k-tiles
// [kz*64, (kz+nkt)*64). LDS rows are 128 B; 16-byte chunks are XOR-swizzled by
// (row&7): global source is inverse-swizzled (gload_lds dest stays linear),
// ds_read applies the same XOR -> 8 lanes per bank-quad = b128 minimum.
// MODE 0: f32 out (+QS), z-sliced by zstride. MODE 1: SwiGLU bf16 out; B-tile
// columns are (gate|up) 16-blocks, so gate/up for one h column land in
// adjacent j-fragments of the SAME lane.
template <int MODE>
__global__ __launch_bounds__(256) void k_gemm_bt(const __bf16* __restrict__ A,
                                                 const __bf16* __restrict__ B,
                                                 void* __restrict__ Out,
                                                 int lda, int nkt, int ldo,
                                                 size_t zstride) {
  __shared__ __bf16 sA[128][64];
  __shared__ __bf16 sB[128][64];
  const int tid = threadIdx.x;
  const int lane = tid & 63;
  const int wid = tid >> 6;
  const int wm = wid >> 1, wn = wid & 1;
  const int row0 = blockIdx.y * 128, col0 = blockIdx.x * 128;
  const int r16 = lane & 15;  // row within a 16-block (m or n)
  const int kq = lane >> 4;   // k-quarter selector
  const int kz = blockIdx.z * nkt;

  f32x4 acc[4][4] = {};

  for (int kt = kz; kt < kz + nkt; ++kt) {
    __syncthreads();  // previous tile's compute done before overwrite
#pragma unroll
    for (int it = 0; it < 4; ++it) {
      int chunk = it * 256 + tid;  // 0..1023 chunks of 16B
      int r = chunk >> 3, kc = chunk & 7;
      int kcs = kc ^ (r & 7);  // inverse swizzle on the global source
      gload_lds16(A + (size_t)(row0 + r) * lda + kt * 64 + kcs * 8,
                  ((__bf16*)sA) + chunk * 8);
      gload_lds16(B + (size_t)(col0 + r) * lda + kt * 64 + kcs * 8,
                  ((__bf16*)sB) + chunk * 8);
    }
    __syncthreads();  // drains vmcnt(0): tiles resident
#pragma unroll
    for (int ks = 0; ks < 2; ++ks) {
      const int chs = ((ks * 4 + kq) ^ (r16 & 7)) << 4;  // swizzled byte chunk
      bf16x8 av[4], bv[4];
#pragma unroll
      for (int i = 0; i < 4; ++i)
        av[i] = *(const bf16x8*)(((const char*)sA) +
                                 (wm * 64 + i * 16 + r16) * 128 + chs);
#pragma unroll
      for (int j = 0; j < 4; ++j)
        bv[j] = *(const bf16x8*)(((const char*)sB) +
                                 (wn * 64 + j * 16 + r16) * 128 + chs);
#pragma unroll
      for (int i = 0; i < 4; ++i)
#pragma unroll
        for (int j = 0; j < 4; ++j)
          acc[i][j] = __builtin_amdgcn_mfma_f32_16x16x32_bf16(av[i], bv[j],
                                                              acc[i][j], 0, 0, 0);
    }
  }

  if constexpr (MODE == 1) {
    __bf16* hout = (__bf16*)Out;
    const int hbase = (col0 + wn * 64) >> 1;
#pragma unroll
    for (int i = 0; i < 4; ++i) {
#pragma unroll
      for (int p = 0; p < 2; ++p) {
#pragma unroll
        for (int r = 0; r < 4; ++r) {
          int row = row0 + wm * 64 + i * 16 + kq * 4 + r;
          float g = acc[i][2 * p][r] * QS;
          float u = acc[i][2 * p + 1][r] * QS;
          float hv = (g / (1.0f + __expf(-g))) * u;
          hout[(size_t)row * ldo + hbase + p * 16 + r16] = (__bf16)hv;
        }
      }
    }
  } else {
    float* out = (float*)Out + blockIdx.z * zstride;
#pragma unroll
    for (int i = 0; i < 4; ++i)
#pragma unroll
      for (int j = 0; j < 4; ++j)
#pragma unroll
        for (int r = 0; r < 4; ++r) {
          int row = row0 + wm * 64 + i * 16 + kq * 4 + r;
          int col = col0 + wn * 64 + j * 16 + r16;
          out[(size_t)row * ldo + col] = acc[i][j][r] * QS;
        }
  }
}

// out = p[z=0] + p[z=1]  (QS already applied in partials)
__global__ __launch_bounds__(256) void k_reduce2(const float* __restrict__ p,
                                                 float* __restrict__ out, int n4) {
  int t = blockIdx.x * 256 + threadIdx.x;
  if (t >= n4) return;
  const float4* a = (const float4*)p;
  const float4* b = (const float4*)(p + (size_t)8192 * 1024);
  float4 va = a[t], vb = b[t];
  ((float4*)out)[t] = make_float4(va.x + vb.x, va.y + vb.y,
                                  va.z + vb.z, va.w + vb.w);
}

// ---------------- launch ----------------

extern "C" void kernel_launch(void* const* d_in, const int* in_sizes, int n_in,
                              void* d_out, int out_size, void* d_ws, size_t ws_size,
                              hipStream_t stream) {
  const float* x = (const float*)d_in[0];
  const int* wg = (const int*)d_in[1];
  const int* wu = (const int*)d_in[2];
  const int* wd = (const int*)d_in[3];

  char* ws = (char*)d_ws;
  __bf16* xb  = (__bf16*)(ws);                          // 16,777,216 B
  __bf16* w1  = (__bf16*)(ws + 16777216);               // 12,582,912 B
  __bf16* wdb = (__bf16*)(ws + 16777216 + 12582912);    //  6,291,456 B
  __bf16* h   = (__bf16*)(ws + 35651584);               // 50,331,648 B
  float*  part = (float*)(ws + 85983232);               // 2x 33,554,432 B (split-K)
  const bool splitk = ws_size >= (size_t)85983232 + 2u * 33554432u;

  k_conv_x<<<4096, 256, 0, stream>>>(x, xb, 1048576);
  k_conv_w1<<<3072, 256, 0, stream>>>(wg, wu, w1);
  k_conv_wd<<<1536, 256, 0, stream>>>(wd, wdb, 393216);

  // GEMM1: [8192,1024] x [6144,1024]^T -> h [8192,3072] (SwiGLU fused)
  k_gemm_bt<1><<<dim3(48, 64, 1), 256, 0, stream>>>(xb, w1, h, 1024, 16, 3072, 0);

  // GEMM2: [8192,3072] x [1024,3072]^T -> out f32 [8192,1024]
  if (splitk) {
    k_gemm_bt<0><<<dim3(8, 64, 2), 256, 0, stream>>>(h, wdb, part, 3072, 24, 1024,
                                                     (size_t)8192 * 1024);
    k_reduce2<<<8192, 256, 0, stream>>>(part, (float*)d_out, 2097152);
  } else {
    k_gemm_bt<0><<<dim3(8, 64, 1), 256, 0, stream>>>(h, wdb, (float*)d_out,
                                                     3072, 48, 1024, 0);
  }
}

// Round 3
// 314.097 us; speedup vs baseline: 1.0656x; 1.0568x over previous
//
#include <hip/hip_runtime.h>
#include <hip/hip_bf16.h>

// SwiGLU MLP: out = (silu(x@wg^T * S) * (x@wu^T * S)) @ wd^T * S,  S = 1/127
// Round 3: distinct kernel names (k_gemm1/k_gemm2) for rocprof attribution;
// GEMM2 gets a chunked XCD-aware block swizzle (fixed z + 16-row y-band + all
// x per XCD) so its A(h) row-panels are shared within one XCD's L2 instead of
// re-fetched 8-16x across XCDs. GEMM1 unchanged (T2-swizzled m97 structure).

typedef __attribute__((ext_vector_type(8))) __bf16 bf16x8;
typedef __attribute__((ext_vector_type(4))) float f32x4;

static constexpr float QS = 1.0f / 127.0f;

__device__ __forceinline__ void gload_lds16(const void* g, void* l) {
  __builtin_amdgcn_global_load_lds(
      (const __attribute__((address_space(1))) void*)g,
      (__attribute__((address_space(3))) void*)l,
      16, 0, 0);
}

// ---------------- conversion kernels ----------------

__global__ __launch_bounds__(256) void k_conv_x(const float* __restrict__ x,
                                                __bf16* __restrict__ xb, int n8) {
  int t = blockIdx.x * 256 + threadIdx.x;
  if (t >= n8) return;
  const float4* p = (const float4*)(x + (size_t)t * 8);
  float4 a = p[0], b = p[1];
  bf16x8 o;
  o[0] = (__bf16)a.x; o[1] = (__bf16)a.y; o[2] = (__bf16)a.z; o[3] = (__bf16)a.w;
  o[4] = (__bf16)b.x; o[5] = (__bf16)b.y; o[6] = (__bf16)b.z; o[7] = (__bf16)b.w;
  *(bf16x8*)(xb + (size_t)t * 8) = o;
}

// W1 row v (0..6143): bb=v>>5, t=v&31; t<16 -> w_gate[16*bb+t] else w_up[16*bb+t-16]
__global__ __launch_bounds__(256) void k_conv_w1(const int* __restrict__ wg,
                                                 const int* __restrict__ wu,
                                                 __bf16* __restrict__ w1) {
  int t = blockIdx.x * 256 + threadIdx.x;  // 6144*128 threads, 8 elems each
  int c8 = t & 127;
  int v = t >> 7;
  int bb = v >> 5, tt = v & 31;
  const int* src = (tt < 16) ? (wg + (size_t)(bb * 16 + tt) * 1024)
                             : (wu + (size_t)(bb * 16 + (tt & 15)) * 1024);
  const int4* p = (const int4*)(src + c8 * 8);
  int4 a = p[0], b = p[1];
  bf16x8 o;
  o[0] = (__bf16)(float)a.x; o[1] = (__bf16)(float)a.y;
  o[2] = (__bf16)(float)a.z; o[3] = (__bf16)(float)a.w;
  o[4] = (__bf16)(float)b.x; o[5] = (__bf16)(float)b.y;
  o[6] = (__bf16)(float)b.z; o[7] = (__bf16)(float)b.w;
  *(bf16x8*)(w1 + (size_t)v * 1024 + c8 * 8) = o;
}

__global__ __launch_bounds__(256) void k_conv_wd(const int* __restrict__ wdn,
                                                 __bf16* __restrict__ wdb, int n8) {
  int t = blockIdx.x * 256 + threadIdx.x;
  if (t >= n8) return;
  const int4* p = (const int4*)(wdn + (size_t)t * 8);
  int4 a = p[0], b = p[1];
  bf16x8 o;
  o[0] = (__bf16)(float)a.x; o[1] = (__bf16)(float)a.y;
  o[2] = (__bf16)(float)a.z; o[3] = (__bf16)(float)a.w;
  o[4] = (__bf16)(float)b.x; o[5] = (__bf16)(float)b.y;
  o[6] = (__bf16)(float)b.z; o[7] = (__bf16)(float)b.w;
  *(bf16x8*)(wdb + (size_t)t * 8) = o;
}

// ---------------- GEMM body (NT), 128x128 tile, BK=64, T2-swizzled ----------
// A [*,lda] bf16 rm, B [*,lda] bf16 rm; k-tiles [kz, kz+nkt)*64. LDS rows are
// 128 B; 16-B chunks XOR-swizzled by (row&7): inverse swizzle on the global
// source (gload_lds dest linear, rule #21) + same XOR on ds_read.
// MODE 0: f32 out (+QS). MODE 1: SwiGLU bf16 out; B cols are (gate|up)
// 16-blocks -> gate/up of one h column sit in adjacent j-frags of SAME lane.
template <int MODE>
__device__ __forceinline__ void gemm_body(const __bf16* __restrict__ A,
                                          const __bf16* __restrict__ B,
                                          void* __restrict__ Out,
                                          int lda, int nkt, int ldo,
                                          int row0, int col0, int kz) {
  __shared__ __bf16 sA[128][64];
  __shared__ __bf16 sB[128][64];
  const int tid = threadIdx.x;
  const int lane = tid & 63;
  const int wid = tid >> 6;
  const int wm = wid >> 1, wn = wid & 1;
  const int r16 = lane & 15;
  const int kq = lane >> 4;

  f32x4 acc[4][4] = {};

  for (int kt = kz; kt < kz + nkt; ++kt) {
    __syncthreads();
#pragma unroll
    for (int it = 0; it < 4; ++it) {
      int chunk = it * 256 + tid;  // 0..1023 chunks of 16B
      int r = chunk >> 3, kc = chunk & 7;
      int kcs = kc ^ (r & 7);  // inverse swizzle on the global source
      gload_lds16(A + (size_t)(row0 + r) * lda + kt * 64 + kcs * 8,
                  ((__bf16*)sA) + chunk * 8);
      gload_lds16(B + (size_t)(col0 + r) * lda + kt * 64 + kcs * 8,
                  ((__bf16*)sB) + chunk * 8);
    }
    __syncthreads();
#pragma unroll
    for (int ks = 0; ks < 2; ++ks) {
      const int chs = ((ks * 4 + kq) ^ (r16 & 7)) << 4;  // swizzled byte chunk
      bf16x8 av[4], bv[4];
#pragma unroll
      for (int i = 0; i < 4; ++i)
        av[i] = *(const bf16x8*)(((const char*)sA) +
                                 (wm * 64 + i * 16 + r16) * 128 + chs);
#pragma unroll
      for (int j = 0; j < 4; ++j)
        bv[j] = *(const bf16x8*)(((const char*)sB) +
                                 (wn * 64 + j * 16 + r16) * 128 + chs);
#pragma unroll
      for (int i = 0; i < 4; ++i)
#pragma unroll
        for (int j = 0; j < 4; ++j)
          acc[i][j] = __builtin_amdgcn_mfma_f32_16x16x32_bf16(av[i], bv[j],
                                                              acc[i][j], 0, 0, 0);
    }
  }

  if constexpr (MODE == 1) {
    __bf16* hout = (__bf16*)Out;
    const int hbase = (col0 + wn * 64) >> 1;
#pragma unroll
    for (int i = 0; i < 4; ++i) {
#pragma unroll
      for (int p = 0; p < 2; ++p) {
#pragma unroll
        for (int r = 0; r < 4; ++r) {
          int row = row0 + wm * 64 + i * 16 + kq * 4 + r;
          float g = acc[i][2 * p][r] * QS;
          float u = acc[i][2 * p + 1][r] * QS;
          float hv = (g / (1.0f + __expf(-g))) * u;
          hout[(size_t)row * ldo + hbase + p * 16 + r16] = (__bf16)hv;
        }
      }
    }
  } else {
    float* out = (float*)Out;
#pragma unroll
    for (int i = 0; i < 4; ++i)
#pragma unroll
      for (int j = 0; j < 4; ++j)
#pragma unroll
        for (int r = 0; r < 4; ++r) {
          int row = row0 + wm * 64 + i * 16 + kq * 4 + r;
          int col = col0 + wn * 64 + j * 16 + r16;
          out[(size_t)row * ldo + col] = acc[i][j][r] * QS;
        }
  }
}

// GEMM1: [8192,1024] x [6144,1024]^T -> h [8192,3072], SwiGLU fused
__global__ __launch_bounds__(256) void k_gemm1(const __bf16* __restrict__ A,
                                               const __bf16* __restrict__ B,
                                               __bf16* __restrict__ H) {
  gemm_body<1>(A, B, H, 1024, 16, 3072, blockIdx.y * 128, blockIdx.x * 128, 0);
}

// GEMM2: [8192,3072] x [1024,3072]^T -> partials f32 [2][8192,1024], split-K=2
// 1-D grid of 1024; chunked XCD swizzle: physical bid b -> logical
// w=(b&7)*128+(b>>3); w = z*512 + y*8 + x. Each XCD (=b&7, round-robin HW
// mapping) gets fixed z, a 16-row y-band, all 8 x -> B z-slice (3.1 MB) is
// L2-resident and A(h) row-panels are shared within the XCD.
__global__ __launch_bounds__(256) void k_gemm2(const __bf16* __restrict__ H,
                                               const __bf16* __restrict__ B,
                                               float* __restrict__ P) {
  int b = blockIdx.x;
  int w = (b & 7) * 128 + (b >> 3);
  int z = w >> 9;
  int rem = w & 511;
  int y = rem >> 3, x = rem & 7;
  gemm_body<0>(H, B, P + (size_t)z * (8192 * 1024), 3072, 24, 1024,
               y * 128, x * 128, z * 24);
}

// out = p[z=0] + p[z=1]
__global__ __launch_bounds__(256) void k_reduce2(const float* __restrict__ p,
                                                 float* __restrict__ out, int n4) {
  int t = blockIdx.x * 256 + threadIdx.x;
  if (t >= n4) return;
  const float4* a = (const float4*)p;
  const float4* b = (const float4*)(p + (size_t)8192 * 1024);
  float4 va = a[t], vb = b[t];
  ((float4*)out)[t] = make_float4(va.x + vb.x, va.y + vb.y,
                                  va.z + vb.z, va.w + vb.w);
}

// fallback (no split-K) if workspace is small
__global__ __launch_bounds__(256) void k_gemm2_nosplit(const __bf16* __restrict__ H,
                                                       const __bf16* __restrict__ B,
                                                       float* __restrict__ O) {
  gemm_body<0>(H, B, O, 3072, 48, 1024, blockIdx.y * 128, blockIdx.x * 128, 0);
}

// ---------------- launch ----------------

extern "C" void kernel_launch(void* const* d_in, const int* in_sizes, int n_in,
                              void* d_out, int out_size, void* d_ws, size_t ws_size,
                              hipStream_t stream) {
  const float* x = (const float*)d_in[0];
  const int* wg = (const int*)d_in[1];
  const int* wu = (const int*)d_in[2];
  const int* wd = (const int*)d_in[3];

  char* ws = (char*)d_ws;
  __bf16* xb  = (__bf16*)(ws);                          // 16,777,216 B
  __bf16* w1  = (__bf16*)(ws + 16777216);               // 12,582,912 B
  __bf16* wdb = (__bf16*)(ws + 16777216 + 12582912);    //  6,291,456 B
  __bf16* h   = (__bf16*)(ws + 35651584);               // 50,331,648 B
  float*  part = (float*)(ws + 85983232);               // 2x 33,554,432 B
  const bool splitk = ws_size >= (size_t)85983232 + 2u * 33554432u;

  k_conv_x<<<4096, 256, 0, stream>>>(x, xb, 1048576);
  k_conv_w1<<<3072, 256, 0, stream>>>(wg, wu, w1);
  k_conv_wd<<<1536, 256, 0, stream>>>(wd, wdb, 393216);

  k_gemm1<<<dim3(48, 64), 256, 0, stream>>>(xb, w1, h);

  if (splitk) {
    k_gemm2<<<1024, 256, 0, stream>>>(h, wdb, part);
    k_reduce2<<<8192, 256, 0, stream>>>(part, (float*)d_out, 2097152);
  } else {
    k_gemm2_nosplit<<<dim3(8, 64), 256, 0, stream>>>(h, wdb, (float*)d_out);
  }
}

// Round 4
// 298.485 us; speedup vs baseline: 1.1213x; 1.0523x over previous
//
#include <hip/hip_runtime.h>
#include <hip/hip_bf16.h>

// SwiGLU MLP: out = (silu(x@wg^T * S) * (x@wu^T * S)) @ wd^T * S,  S = 1/127
// Round 4: both GEMMs ported to the 256^2 8-phase schedule (T3+T4+T5):
// 512 threads (8 waves, 2M x 4N), BK=64, 128 KiB double-buffered LDS,
// raw s_barrier (no vmcnt(0) drain), counted s_waitcnt vmcnt(4) once per
// K-tile, s_setprio around each 16-MFMA cluster, T2 XOR-swizzle kept.
// Stage-slot ledger (per tile T, buf c = T&1):
//   ph1: ds A(mg0)+B(ng0), stage T+1:Ah1 -> buf c^1 (idle)      [16 MFMA q00]
//   ph2: ds B(ng1),        stage T+1:Bh1 -> buf c^1 (idle)      [16 MFMA q01]
//   ph3: ds A(mg1),        stage T+2:Bh0 -> buf c (B reads done)[16 MFMA q10]
//   ph4: -,                stage T+2:Ah0 -> buf c (A reads done)[16 MFMA q11]
//        vmcnt(4) -> everything through ph2 landed => tile T+1 complete.
// Tail stages clamp the source tile (constant ledger, dead regions).

typedef __attribute__((ext_vector_type(8))) __bf16 bf16x8;
typedef __attribute__((ext_vector_type(4))) float f32x4;

static constexpr float QS = 1.0f / 127.0f;

#define BAR()   asm volatile("s_barrier" ::: "memory")
#define VMCNT4() asm volatile("s_waitcnt vmcnt(4)" ::: "memory")
#define VMCNT0() asm volatile("s_waitcnt vmcnt(0)" ::: "memory")
#define PRIO1() __builtin_amdgcn_s_setprio(1)
#define PRIO0() __builtin_amdgcn_s_setprio(0)

__device__ __forceinline__ void gload_lds16(const void* g, void* l) {
  __builtin_amdgcn_global_load_lds(
      (const __attribute__((address_space(1))) void*)g,
      (__attribute__((address_space(3))) void*)l,
      16, 0, 0);
}

// ---------------- conversion kernels ----------------

__global__ __launch_bounds__(256) void k_conv_x(const float* __restrict__ x,
                                                __bf16* __restrict__ xb, int n8) {
  int t = blockIdx.x * 256 + threadIdx.x;
  if (t >= n8) return;
  const float4* p = (const float4*)(x + (size_t)t * 8);
  float4 a = p[0], b = p[1];
  bf16x8 o;
  o[0] = (__bf16)a.x; o[1] = (__bf16)a.y; o[2] = (__bf16)a.z; o[3] = (__bf16)a.w;
  o[4] = (__bf16)b.x; o[5] = (__bf16)b.y; o[6] = (__bf16)b.z; o[7] = (__bf16)b.w;
  *(bf16x8*)(xb + (size_t)t * 8) = o;
}

__global__ __launch_bounds__(256) void k_conv_w1(const int* __restrict__ wg,
                                                 const int* __restrict__ wu,
                                                 __bf16* __restrict__ w1) {
  int t = blockIdx.x * 256 + threadIdx.x;
  int c8 = t & 127;
  int v = t >> 7;
  int bb = v >> 5, tt = v & 31;
  const int* src = (tt < 16) ? (wg + (size_t)(bb * 16 + tt) * 1024)
                             : (wu + (size_t)(bb * 16 + (tt & 15)) * 1024);
  const int4* p = (const int4*)(src + c8 * 8);
  int4 a = p[0], b = p[1];
  bf16x8 o;
  o[0] = (__bf16)(float)a.x; o[1] = (__bf16)(float)a.y;
  o[2] = (__bf16)(float)a.z; o[3] = (__bf16)(float)a.w;
  o[4] = (__bf16)(float)b.x; o[5] = (__bf16)(float)b.y;
  o[6] = (__bf16)(float)b.z; o[7] = (__bf16)(float)b.w;
  *(bf16x8*)(w1 + (size_t)v * 1024 + c8 * 8) = o;
}

__global__ __launch_bounds__(256) void k_conv_wd(const int* __restrict__ wdn,
                                                 __bf16* __restrict__ wdb, int n8) {
  int t = blockIdx.x * 256 + threadIdx.x;
  if (t >= n8) return;
  const int4* p = (const int4*)(wdn + (size_t)t * 8);
  int4 a = p[0], b = p[1];
  bf16x8 o;
  o[0] = (__bf16)(float)a.x; o[1] = (__bf16)(float)a.y;
  o[2] = (__bf16)(float)a.z; o[3] = (__bf16)(float)a.w;
  o[4] = (__bf16)(float)b.x; o[5] = (__bf16)(float)b.y;
  o[6] = (__bf16)(float)b.z; o[7] = (__bf16)(float)b.w;
  *(bf16x8*)(wdb + (size_t)t * 8) = o;
}

// -------- 256x256 8-phase GEMM (NT both inputs row-major [*, LDAK]) --------
// MODE 0: f32 out (*QS). MODE 1: SwiGLU bf16 out (B cols = gate|up 16-blocks).

#define MFMA16(MG, NG)                                                         \
  _Pragma("unroll") for (int mi = 0; mi < 4; ++mi) {                           \
    _Pragma("unroll") for (int nj = 0; nj < 2; ++nj) {                         \
      acc[(MG)*4 + mi][(NG)*2 + nj] = __builtin_amdgcn_mfma_f32_16x16x32_bf16( \
          af[mi][0], bf[NG][nj][0], acc[(MG)*4 + mi][(NG)*2 + nj], 0, 0, 0);   \
      acc[(MG)*4 + mi][(NG)*2 + nj] = __builtin_amdgcn_mfma_f32_16x16x32_bf16( \
          af[mi][1], bf[NG][nj][1], acc[(MG)*4 + mi][(NG)*2 + nj], 0, 0, 0);   \
    }                                                                          \
  }

#define LDAF(MG)                                                               \
  _Pragma("unroll") for (int mi = 0; mi < 4; ++mi) {                           \
    af[mi][0] = *(const bf16x8*)(aL + ((MG)*64 + mi * 16 + r16) * 128 + s0);   \
    af[mi][1] = *(const bf16x8*)(aL + ((MG)*64 + mi * 16 + r16) * 128 + s1);   \
  }

#define LDBF(NG)                                                               \
  _Pragma("unroll") for (int nj = 0; nj < 2; ++nj) {                           \
    bf[NG][nj][0] = *(const bf16x8*)(bL + (bro + (NG)*32 + nj * 16) * 128 + s0); \
    bf[NG][nj][1] = *(const bf16x8*)(bL + (bro + (NG)*32 + nj * 16) * 128 + s1); \
  }

template <int MODE, int LDAK, int NT, int LDO>
__device__ __forceinline__ void gemm8_body(const __bf16* __restrict__ A,
                                           const __bf16* __restrict__ Bp,
                                           void* __restrict__ Out,
                                           int row0, int col0, int kz) {
  __shared__ __bf16 sA[2][2][128][64];   // [buf][half][row][k]
  __shared__ __bf16 sB[2][2][128][64];
  const int tid = threadIdx.x;           // 0..511
  const int lane = tid & 63;
  const int wid = tid >> 6;              // 0..7
  const int wm = wid >> 2, wn = wid & 3; // 2 x 4 waves
  const int r16 = lane & 15;
  const int kq = lane >> 4;

  auto STG = [&](__bf16* dst, const __bf16* src, int rbase, int kt) {
    int r0 = tid >> 3;
    int c0 = (tid & 7) ^ (r0 & 7);               // inverse T2 swizzle on src
    int r1 = 64 + r0;                            // (512+tid)>>3 ; same c
    gload_lds16(src + (size_t)(rbase + r0) * LDAK + kt * 64 + c0 * 8,
                dst + tid * 8);
    gload_lds16(src + (size_t)(rbase + r1) * LDAK + kt * 64 + c0 * 8,
                dst + (512 + tid) * 8);
  };

  f32x4 acc[8][4] = {};

  // prologue: T0 complete + T1:{Bh0, Ah0}
  STG(&sA[0][0][0][0], A, row0, kz);
  STG(&sB[0][0][0][0], Bp, col0, kz);
  STG(&sA[0][1][0][0], A, row0 + 128, kz);
  STG(&sB[0][1][0][0], Bp, col0 + 128, kz);
  const int kt1 = kz + (NT > 1 ? 1 : 0);
  STG(&sB[1][0][0][0], Bp, col0, kt1);
  STG(&sA[1][0][0][0], A, row0, kt1);
  VMCNT4();   // T0 landed; T1:{Bh0,Ah0} in flight
  BAR();

  for (int t = 0; t < NT; ++t) {
    const int c = t & 1;
    const char* aL = (const char*)&sA[c][wm][0][0];
    const char* bL = (const char*)&sB[c][wn >> 1][0][0];
    const int bro = (wn & 1) * 64 + r16;
    const int s0 = ((kq) ^ (r16 & 7)) << 4;
    const int s1 = ((4 + kq) ^ (r16 & 7)) << 4;
    const int k1 = kz + (t + 1 < NT ? t + 1 : NT - 1);
    const int k2 = kz + (t + 2 < NT ? t + 2 : NT - 1);
    bf16x8 af[4][2], bf[2][2][2];

    // ---- phase 1: q(0,0)
    LDAF(0);
    LDBF(0);
    STG(&sA[c ^ 1][1][0][0], A, row0 + 128, k1);   // T+1 Ah1 (idle buf)
    BAR();
    PRIO1(); MFMA16(0, 0); PRIO0();
    BAR();
    // ---- phase 2: q(0,1)
    LDBF(1);
    STG(&sB[c ^ 1][1][0][0], Bp, col0 + 128, k1);  // T+1 Bh1 (idle buf)
    BAR();
    PRIO1(); MFMA16(0, 1); PRIO0();
    BAR();
    // ---- phase 3: q(1,0)  (B ng0 kept in regs)
    LDAF(1);
    STG(&sB[c][0][0][0], Bp, col0, k2);            // T+2 Bh0 (B reads done)
    BAR();
    PRIO1(); MFMA16(1, 0); PRIO0();
    BAR();
    // ---- phase 4: q(1,1)  (A mg1 + B ng1 kept in regs)
    STG(&sA[c][0][0][0], A, row0, k2);             // T+2 Ah0 (A reads done)
    BAR();
    PRIO1(); MFMA16(1, 1); PRIO0();
    VMCNT4();   // tile T+1 fully landed; 2 half-tiles stay in flight
    BAR();
  }

  if constexpr (MODE == 1) {
    __bf16* hout = (__bf16*)Out;
    const int hbase = (col0 + wn * 64) >> 1;
#pragma unroll
    for (int i = 0; i < 8; ++i) {
#pragma unroll
      for (int p = 0; p < 2; ++p) {
#pragma unroll
        for (int rr = 0; rr < 4; ++rr) {
          int row = row0 + wm * 128 + i * 16 + kq * 4 + rr;
          float g = acc[i][2 * p][rr] * QS;
          float u = acc[i][2 * p + 1][rr] * QS;
          float hv = (g / (1.0f + __expf(-g))) * u;
          hout[(size_t)row * LDO + hbase + p * 16 + r16] = (__bf16)hv;
        }
      }
    }
  } else {
    float* out = (float*)Out;
#pragma unroll
    for (int i = 0; i < 8; ++i)
#pragma unroll
      for (int j = 0; j < 4; ++j)
#pragma unroll
        for (int rr = 0; rr < 4; ++rr) {
          int row = row0 + wm * 128 + i * 16 + kq * 4 + rr;
          int col = col0 + wn * 64 + j * 16 + r16;
          out[(size_t)row * LDO + col] = acc[i][j][rr] * QS;
        }
  }
  VMCNT0();   // drain clamped tail stages before LDS handoff to next block
}

// GEMM1: [8192,1024] x [6144,1024]^T -> h [8192,3072], SwiGLU fused
__global__ __launch_bounds__(512, 2) void k_gemm1_8p(const __bf16* __restrict__ A,
                                                     const __bf16* __restrict__ B,
                                                     __bf16* __restrict__ H) {
  gemm8_body<1, 1024, 16, 3072>(A, B, H, blockIdx.y * 256, blockIdx.x * 256, 0);
}

// GEMM2: [8192,3072] x [1024,3072]^T, split-K=2 -> partials f32 [2][8192,1024]
// 256 blocks; chunked XCD swizzle: b -> w=(b&7)*32+(b>>3); w = z*128 + y*4 + x
__global__ __launch_bounds__(512, 2) void k_gemm2_8p(const __bf16* __restrict__ H,
                                                     const __bf16* __restrict__ B,
                                                     float* __restrict__ P) {
  int b = blockIdx.x;
  int w = (b & 7) * 32 + (b >> 3);
  int z = w >> 7;
  int rem = w & 127;
  int y = rem >> 2, x = rem & 3;
  gemm8_body<0, 3072, 24, 1024>(H, B, P + (size_t)z * (8192 * 1024),
                                y * 256, x * 256, z * 24);
}

// fallback (no split-K) if workspace is small
__global__ __launch_bounds__(512, 2) void k_gemm2_8p_ns(const __bf16* __restrict__ H,
                                                        const __bf16* __restrict__ B,
                                                        float* __restrict__ O) {
  gemm8_body<0, 3072, 48, 1024>(H, B, O, blockIdx.y * 256, blockIdx.x * 256, 0);
}

// out = p[z=0] + p[z=1]
__global__ __launch_bounds__(256) void k_reduce2(const float* __restrict__ p,
                                                 float* __restrict__ out, int n4) {
  int t = blockIdx.x * 256 + threadIdx.x;
  if (t >= n4) return;
  const float4* a = (const float4*)p;
  const float4* b = (const float4*)(p + (size_t)8192 * 1024);
  float4 va = a[t], vb = b[t];
  ((float4*)out)[t] = make_float4(va.x + vb.x, va.y + vb.y,
                                  va.z + vb.z, va.w + vb.w);
}

// ---------------- launch ----------------

extern "C" void kernel_launch(void* const* d_in, const int* in_sizes, int n_in,
                              void* d_out, int out_size, void* d_ws, size_t ws_size,
                              hipStream_t stream) {
  const float* x = (const float*)d_in[0];
  const int* wg = (const int*)d_in[1];
  const int* wu = (const int*)d_in[2];
  const int* wd = (const int*)d_in[3];

  char* ws = (char*)d_ws;
  __bf16* xb  = (__bf16*)(ws);                          // 16,777,216 B
  __bf16* w1  = (__bf16*)(ws + 16777216);               // 12,582,912 B
  __bf16* wdb = (__bf16*)(ws + 16777216 + 12582912);    //  6,291,456 B
  __bf16* h   = (__bf16*)(ws + 35651584);               // 50,331,648 B
  float*  part = (float*)(ws + 85983232);               // 2x 33,554,432 B
  const bool splitk = ws_size >= (size_t)85983232 + 2u * 33554432u;

  k_conv_x<<<4096, 256, 0, stream>>>(x, xb, 1048576);
  k_conv_w1<<<3072, 256, 0, stream>>>(wg, wu, w1);
  k_conv_wd<<<1536, 256, 0, stream>>>(wd, wdb, 393216);

  k_gemm1_8p<<<dim3(24, 32), 512, 0, stream>>>(xb, w1, h);

  if (splitk) {
    k_gemm2_8p<<<256, 512, 0, stream>>>(h, wdb, part);
    k_reduce2<<<8192, 256, 0, stream>>>(part, (float*)d_out, 2097152);
  } else {
    k_gemm2_8p_ns<<<dim3(4, 32), 512, 0, stream>>>(h, wdb, (float*)d_out);
  }
}